// Round 1
// 400.026 us; speedup vs baseline: 1.0189x; 1.0189x over previous
//
#include <hip/hip_runtime.h>
#include <hip/hip_bf16.h>
#include <math.h>

// MHA block: B=4, S=2048, D=1024, H=16, DK=64.
// R6: attn — phase-split per kt so K/V fragments are read from LDS ONCE and
// reused across both mt q-sub-tiles (36 -> 20 b128 reads per thread-kt; LDS
// pipe was the modeled bottleneck at ~133us). P slice reused serially
// (write mt0 -> read pf0 -> write mt1 -> read pf1; same-wave in-order DS,
// same hazard pattern the R5 kernel already relied on). LDS stays 40KB ->
// 4 blocks/CU. GEMM unchanged from R5.

namespace {

constexpr int Bb = 4, Ss = 2048, Dd = 1024, Hh = 16, DKk = 64;

typedef __bf16 bf16;
typedef __attribute__((ext_vector_type(8))) __bf16 bf16x8;
typedef __attribute__((ext_vector_type(4))) float f32x4;

__device__ __forceinline__ bf16x8 pack8(float4 a, float4 b) {
  bf16x8 r;
  r[0] = (__bf16)a.x; r[1] = (__bf16)a.y; r[2] = (__bf16)a.z; r[3] = (__bf16)a.w;
  r[4] = (__bf16)b.x; r[5] = (__bf16)b.y; r[6] = (__bf16)b.z; r[7] = (__bf16)b.w;
  return r;
}

__device__ __forceinline__ void gl_lds16(const bf16* g, bf16* l) {
  __builtin_amdgcn_global_load_lds((const __attribute__((address_space(1))) void*)g,
                                   (__attribute__((address_space(3))) void*)l, 16, 0, 0);
}

// fp32 -> bf16 converts: blocks [0,4096) convert x (8.39M elts), [4096,4608) convert w (1M).
__global__ __launch_bounds__(256) void cvt_pair(const float* __restrict__ x, bf16* __restrict__ xd,
                                                const float* __restrict__ ws, bf16* __restrict__ wd) {
  const int bid = blockIdx.x;
  const float* s; bf16* d; size_t idx;
  if (bid < 4096) { s = x; d = xd; idx = (size_t)bid * 256 + threadIdx.x; }
  else { s = ws; d = wd; idx = (size_t)(bid - 4096) * 256 + threadIdx.x; }
  idx *= 8;
  float4 f0 = *(const float4*)(s + idx), f1 = *(const float4*)(s + idx + 4);
  *(bf16x8*)(d + idx) = pack8(f0, f1);
}

__global__ __launch_bounds__(256) void cvt_w(const float* __restrict__ ws, bf16* __restrict__ wd) {
  size_t idx = ((size_t)blockIdx.x * 256 + threadIdx.x) * 8;
  float4 f0 = *(const float4*)(ws + idx), f1 = *(const float4*)(ws + idx + 4);
  *(bf16x8*)(wd + idx) = pack8(f0, f1);
}

// C = A(8192x1024) * W(1024x1024)^T, bf16 in, 128x128 tile, BK=32, 4 waves (2x2 of 64x64).
// Double-buffered global_load_lds: prefetch kt+1 during MFMA on kt; barrier drain
// then waits on loads a full compute-phase old.
template <int MODE>
__global__ __launch_bounds__(256) void mha_gemm(const bf16* __restrict__ A,
                                                const bf16* __restrict__ W,
                                                void* __restrict__ dstv) {
  __shared__ __align__(16) bf16 As[2][128][32];
  __shared__ __align__(16) bf16 Bs[2][128][32];
  const int tid = threadIdx.x;
  const int bm0 = blockIdx.x * 128, bn0 = blockIdx.y * 128;
  const int w = tid >> 6, lane = tid & 63, l16 = lane & 15, quad = lane >> 4;
  const int wm = (w >> 1) * 64, wn = (w & 1) * 64;
  const int lr = lane >> 2, lc = (lane & 3) * 8;

  const bf16* Ag = A + (size_t)(bm0 + w * 32 + lr) * Dd + lc;
  const bf16* Wg = W + (size_t)(bn0 + w * 32 + lr) * Dd + lc;

  f32x4 acc[4][4] = {};

  // prologue: stage k-tile 0 into buf 0
  gl_lds16(Ag, &As[0][w * 32][0]);
  gl_lds16(Ag + 16 * Dd, &As[0][w * 32 + 16][0]);
  gl_lds16(Wg, &Bs[0][w * 32][0]);
  gl_lds16(Wg + 16 * Dd, &Bs[0][w * 32 + 16][0]);
  __syncthreads();

  for (int kt = 0; kt < 32; ++kt) {
    const int cur = kt & 1, nxt = cur ^ 1;
    if (kt < 31) {
      const int ko = (kt + 1) * 32;
      gl_lds16(Ag + ko, &As[nxt][w * 32][0]);
      gl_lds16(Ag + ko + 16 * Dd, &As[nxt][w * 32 + 16][0]);
      gl_lds16(Wg + ko, &Bs[nxt][w * 32][0]);
      gl_lds16(Wg + ko + 16 * Dd, &Bs[nxt][w * 32 + 16][0]);
    }
    bf16x8 af[4], bw[4];
#pragma unroll
    for (int i = 0; i < 4; ++i) af[i] = *(bf16x8*)&As[cur][wm + i * 16 + l16][quad * 8];
#pragma unroll
    for (int i = 0; i < 4; ++i) bw[i] = *(bf16x8*)&Bs[cur][wn + i * 16 + l16][quad * 8];
#pragma unroll
    for (int mt = 0; mt < 4; ++mt)
#pragma unroll
      for (int nt = 0; nt < 4; ++nt)
        acc[mt][nt] =
            __builtin_amdgcn_mfma_f32_16x16x32_bf16(af[mt], bw[nt], acc[mt][nt], 0, 0, 0);
    __syncthreads();  // drains nxt DMA (issued before compute) + orders LDS reuse
  }

  // C/D layout: col = lane&15, row = quad*4 + r
  if constexpr (MODE == 2) {
    float* out = (float*)dstv;
#pragma unroll
    for (int mt = 0; mt < 4; ++mt)
#pragma unroll
      for (int nt = 0; nt < 4; ++nt) {
        const int gcol = bn0 + wn + nt * 16 + l16;
        const int grow0 = bm0 + wm + mt * 16 + quad * 4;
#pragma unroll
        for (int r = 0; r < 4; ++r) out[(size_t)(grow0 + r) * Dd + gcol] = acc[mt][nt][r];
      }
  } else if constexpr (MODE == 1) {
    bf16* vt = (bf16*)dstv;
#pragma unroll
    for (int mt = 0; mt < 4; ++mt)
#pragma unroll
      for (int nt = 0; nt < 4; ++nt) {
        const int gcol = bn0 + wn + nt * 16 + l16;
        const int h = gcol >> 6, dk = gcol & 63;
#pragma unroll
        for (int r = 0; r < 4; ++r) {
          const int grow = bm0 + wm + mt * 16 + quad * 4 + r;
          const int b = grow >> 11, s = grow & (Ss - 1);
          vt[((size_t)(b * Hh + h) * DKk + dk) * Ss + s] = (bf16)acc[mt][nt][r];
        }
      }
  } else {
    bf16* qp = (bf16*)dstv;
#pragma unroll
    for (int mt = 0; mt < 4; ++mt)
#pragma unroll
      for (int nt = 0; nt < 4; ++nt) {
        const int gcol = bn0 + wn + nt * 16 + l16;
        const int h = gcol >> 6, dk = gcol & 63;
        const float invf = exp2f((float)(dk >> 1) * -0.4152410118609203f);
        const float sgn = (dk & 1) ? 1.0f : -1.0f;
#pragma unroll
        for (int r = 0; r < 4; ++r) {
          const int grow = bm0 + wm + mt * 16 + quad * 4 + r;
          const int b = grow >> 11, s = grow & (Ss - 1);
          const float v = acc[mt][nt][r];
          const float ov = __shfl_xor(v, 1);
          float sn, cs;
          __sincosf((float)s * invf, &sn, &cs);
          const float rot = v * cs + sgn * ov * sn;
          qp[((size_t)(b * Hh + h) * Ss + s) * DKk + dk] = (bf16)rot;
        }
      }
  }
}

// Flash attention R6: 128 q-rows x one (b,h) per block; 4 waves x 32 rows (2 mt blocks);
// 64-key tiles, double-buffered gl_lds; mask folded into MFMA acc init; l via ones-MFMA.
// Per-kt phase split: QK for BOTH mt with single-pass kf reads (sc[2][4] live),
// then P write/read interleaved per mt (Pb slice reused serially), then a single
// PV pass where each vf read feeds both mt accumulators.
// LDS: Ks 16K dbuf + Vs 16K dbuf + P 8K = 40960 B -> 4 blocks/CU.
__global__ __launch_bounds__(256, 4) void mha_attn(const bf16* __restrict__ Qp,
                                                   const bf16* __restrict__ Kp,
                                                   const bf16* __restrict__ Vt,
                                                   const int* __restrict__ maskG,
                                                   bf16* __restrict__ Xo) {
  __shared__ __align__(16) bf16 Ks[2][64][64];  // [buf][key][dk], XOR-swizzled 16B chunks
  __shared__ __align__(16) bf16 Vs[2][64][64];  // [buf][dk][key], XOR-swizzled 16B chunks
  __shared__ __align__(16) bf16 Pbuf[4][1024];  // per-wave P slice (16 rows x 64 keys)

  constexpr float c1 = 0.18033688011112042f;   // 0.125 * log2(e)
  constexpr float c2 = -17.312340490667562f;   // -12 * log2(e)

  const int tid = threadIdx.x;
  const int bh = blockIdx.y, b = bh >> 4, h = bh & 15;
  const int q0 = blockIdx.x * 128;
  const int w = tid >> 6, lane = tid & 63, l16 = lane & 15, quad = lane >> 4;
  const int swz = l16 & 7;
  const size_t hbase = (size_t)bh * Ss * DKk;

  {  // stage Q tile [128 x 64] through the Ks dbuf area (8192 elts, exactly fits)
    bf16* Qst = &Ks[0][0][0];
    const int row = tid >> 1, hf = tid & 1;
    const bf16* src = Qp + hbase + (size_t)(q0 + row) * DKk + hf * 32;
#pragma unroll
    for (int cc = 0; cc < 4; ++cc)
      *(int4*)&Qst[(((hf * 4 + cc) * 128) + row) * 8] = *(const int4*)(src + cc * 8);
  }
  __syncthreads();
  // hoist Q fragments (A-layout: m -> q-row w*32+mt*16+l16, k=kk*32+quad*8+j)
  bf16x8 qf[2][2];
  {
    const bf16* Qst = &Ks[0][0][0];
#pragma unroll
    for (int mt = 0; mt < 2; ++mt)
#pragma unroll
      for (int kk = 0; kk < 2; ++kk)
        qf[mt][kk] = *(bf16x8*)&Qst[(((kk * 4 + quad) * 128) + w * 32 + mt * 16 + l16) * 8];
  }
  __syncthreads();  // all hoists done before K DMA overwrites Ks

  // staging lane geometry: 8 rows x 8 chunks per issue; swizzle chunk ^= row&7
  const int srow = lane >> 3, schunk = (lane & 7) ^ (srow & 7);
  const bf16* Kg = Kp + hbase + (size_t)(w * 16 + srow) * DKk + schunk * 8;
  const bf16* Vg = Vt + ((size_t)bh * DKk + w * 16 + srow) * Ss + schunk * 8;
  const int* Mg = maskG + b * Ss + l16;

  int mcur[4], mnext[4];
  // prologue: stage tile 0
#pragma unroll
  for (int i = 0; i < 2; ++i) {
    gl_lds16(Kg + (size_t)i * 8 * DKk, &Ks[0][w * 16 + i * 8][0]);
    gl_lds16(Vg + i * 8 * Ss, &Vs[0][w * 16 + i * 8][0]);
  }
#pragma unroll
  for (int nt = 0; nt < 4; ++nt) mcur[nt] = Mg[nt * 16];
  __syncthreads();  // drains tile-0 DMA

  f32x4 o[2][4] = {};
  f32x4 lo[2] = {};
  bf16* Pb = &Pbuf[w][0];

  // ones B-operand for the l-accumulating MFMA (registers only, no LDS)
  bf16x8 vones;
#pragma unroll
  for (int i = 0; i < 8; ++i) vones[i] = (__bf16)1.0f;

  for (int kt = 0; kt < 32; ++kt) {
    const int cur = kt & 1, nxt = cur ^ 1;
    if (kt < 31) {  // prefetch tile kt+1 (drained at this iteration's end barrier)
      const size_t k0n = (size_t)(kt + 1) * 64;
#pragma unroll
      for (int i = 0; i < 2; ++i) {
        gl_lds16(Kg + k0n * DKk + (size_t)i * 8 * DKk, &Ks[nxt][w * 16 + i * 8][0]);
        gl_lds16(Vg + k0n + i * 8 * Ss, &Vs[nxt][w * 16 + i * 8][0]);
      }
#pragma unroll
      for (int nt = 0; nt < 4; ++nt) mnext[nt] = Mg[k0n + nt * 16];
    }

    // ---- QK phase: S = Q K^T for BOTH mt, each kf read ONCE ----
    // mask bias folded into accumulator init: masked cols start at -1e9 ->
    // exp2 underflows to exact 0 (matches ref select)
    f32x4 sc[2][4];
#pragma unroll
    for (int nt = 0; nt < 4; ++nt) {
      const float bv = (mcur[nt] != 0) ? 0.0f : -1e9f;
#pragma unroll
      for (int r = 0; r < 4; ++r) { sc[0][nt][r] = bv; sc[1][nt][r] = bv; }
    }
#pragma unroll
    for (int kk = 0; kk < 2; ++kk)
#pragma unroll
      for (int nt = 0; nt < 4; ++nt) {
        bf16x8 kf = *(bf16x8*)&Ks[cur][nt * 16 + l16][((kk * 4 + quad) ^ swz) * 8];
        sc[0][nt] = __builtin_amdgcn_mfma_f32_16x16x32_bf16(qf[0][kk], kf, sc[0][nt], 0, 0, 0);
        sc[1][nt] = __builtin_amdgcn_mfma_f32_16x16x32_bf16(qf[1][kk], kf, sc[1][nt], 0, 0, 0);
      }

    // ---- softmax + P staging, mt0 then mt1 through the SAME Pb slice ----
    // (same-wave DS ops execute in order: write mt0 -> read pf0 -> write mt1
    //  -> read pf1 is safe; R5 already relied on this across mt iterations)
    bf16x8 pf0[2], pf1[2];
#pragma unroll
    for (int nt = 0; nt < 4; ++nt) {
      const int c = nt * 2 + (l16 >> 3);
      const int jj = l16 & 7;
#pragma unroll
      for (int r = 0; r < 4; ++r)
        Pb[(c * 16 + quad * 4 + r) * 8 + jj] = (bf16)exp2f(fmaf(sc[0][nt][r], c1, c2));
    }
#pragma unroll
    for (int kk = 0; kk < 2; ++kk)
      pf0[kk] = *(bf16x8*)(Pb + ((kk * 4 + quad) * 16 + l16) * 8);
#pragma unroll
    for (int nt = 0; nt < 4; ++nt) {
      const int c = nt * 2 + (l16 >> 3);
      const int jj = l16 & 7;
#pragma unroll
      for (int r = 0; r < 4; ++r)
        Pb[(c * 16 + quad * 4 + r) * 8 + jj] = (bf16)exp2f(fmaf(sc[1][nt][r], c1, c2));
    }
#pragma unroll
    for (int kk = 0; kk < 2; ++kk)
      pf1[kk] = *(bf16x8*)(Pb + ((kk * 4 + quad) * 16 + l16) * 8);

    // ---- PV phase: each vf read ONCE, feeds both mt; l via ones-MFMA ----
#pragma unroll
    for (int kk = 0; kk < 2; ++kk) {
      lo[0] = __builtin_amdgcn_mfma_f32_16x16x32_bf16(pf0[kk], vones, lo[0], 0, 0, 0);
      lo[1] = __builtin_amdgcn_mfma_f32_16x16x32_bf16(pf1[kk], vones, lo[1], 0, 0, 0);
#pragma unroll
      for (int nt = 0; nt < 4; ++nt) {
        bf16x8 vf = *(bf16x8*)&Vs[cur][nt * 16 + l16][((kk * 4 + quad) ^ swz) * 8];
        o[0][nt] = __builtin_amdgcn_mfma_f32_16x16x32_bf16(pf0[kk], vf, o[0][nt], 0, 0, 0);
        o[1][nt] = __builtin_amdgcn_mfma_f32_16x16x32_bf16(pf1[kk], vf, o[1][nt], 0, 0, 0);
      }
    }
    __syncthreads();  // all waves done with buf cur; prefetch of nxt drained here
#pragma unroll
    for (int nt = 0; nt < 4; ++nt) mcur[nt] = mnext[nt];
  }

  // epilogue: O / l -> Xo [B*S, H*DK] bf16  (lo identical across the 16 cols of a row)
#pragma unroll
  for (int mt = 0; mt < 2; ++mt)
#pragma unroll
    for (int nt = 0; nt < 4; ++nt)
#pragma unroll
      for (int r = 0; r < 4; ++r) {
        const int srw = q0 + w * 32 + mt * 16 + quad * 4 + r;
        const int dk = nt * 16 + l16;
        Xo[(size_t)(b * Ss + srw) * Dd + h * DKk + dk] = (bf16)(o[mt][nt][r] / lo[mt][r]);
      }
}

}  // namespace

extern "C" void kernel_launch(void* const* d_in, const int* in_sizes, int n_in,
                              void* d_out, int out_size, void* d_ws, size_t ws_size,
                              hipStream_t stream) {
  (void)in_sizes; (void)n_in; (void)out_size; (void)ws_size;
  const float* q = (const float*)d_in[0];
  const float* k = (const float*)d_in[1];
  const float* v = (const float*)d_in[2];
  const int* mask = (const int*)d_in[3];
  const float* w_q = (const float*)d_in[4];
  const float* w_k = (const float*)d_in[5];
  const float* w_v = (const float*)d_in[6];
  const float* w_o = (const float*)d_in[7];
  float* out = (float*)d_out;

  const size_t n_elem = (size_t)Bb * Hh * Ss * DKk;  // 8.39M
  bf16* buf0 = (bf16*)d_ws;         // 16.78 MB: bf16 A staging, later Xo
  bf16* wbuf = buf0 + n_elem;       // 2 MB: bf16 weight staging (reused per GEMM)
  bf16* Qp = wbuf + (1 << 20);      // [B,H,S,DK] rope'd
  bf16* Kp = Qp + n_elem;           // [B,H,S,DK] rope'd
  bf16* Vt = Kp + n_elem;           // [B,H,DK,S]
  // total ws use: 69.2 MB

  dim3 g(64, 8), blk(256);
  cvt_pair<<<4608, blk, 0, stream>>>(q, buf0, w_q, wbuf);
  mha_gemm<0><<<g, blk, 0, stream>>>(buf0, wbuf, (void*)Qp);
  cvt_pair<<<4608, blk, 0, stream>>>(k, buf0, w_k, wbuf);
  mha_gemm<0><<<g, blk, 0, stream>>>(buf0, wbuf, (void*)Kp);
  cvt_pair<<<4608, blk, 0, stream>>>(v, buf0, w_v, wbuf);
  mha_gemm<1><<<g, blk, 0, stream>>>(buf0, wbuf, (void*)Vt);
  mha_attn<<<dim3(16, 64), blk, 0, stream>>>(Qp, Kp, Vt, mask, buf0);
  cvt_w<<<512, blk, 0, stream>>>(w_o, wbuf);
  mha_gemm<2><<<g, blk, 0, stream>>>(buf0, wbuf, (void*)out);
}

// Round 2
// 390.768 us; speedup vs baseline: 1.0430x; 1.0237x over previous
//
#include <hip/hip_runtime.h>
#include <hip/hip_bf16.h>
#include <math.h>

// MHA block: B=4, S=2048, D=1024, H=16, DK=64.
// R7: GEMM — BK 32 -> 64 (16 K-iterations instead of 32; each barrier's
// vmcnt(0) prefetch-drain now amortized over 32 MFMA instead of 16).
// BK=64 row stride = 128B => 16-way LDS bank conflict on ds_read_b128, fixed
// with the XOR-chunk swizzle already validated in mha_attn (pre-swizzled
// per-lane global source + XOR on read; gl_lds dest stays linear).
// LDS 64KB -> 2 blocks/CU, exactly matching the 512-block grid (2/CU).
// Attn unchanged from R6 (136us; P-path transpose is the next lever there).

namespace {

constexpr int Bb = 4, Ss = 2048, Dd = 1024, Hh = 16, DKk = 64;

typedef __bf16 bf16;
typedef __attribute__((ext_vector_type(8))) __bf16 bf16x8;
typedef __attribute__((ext_vector_type(4))) float f32x4;

__device__ __forceinline__ bf16x8 pack8(float4 a, float4 b) {
  bf16x8 r;
  r[0] = (__bf16)a.x; r[1] = (__bf16)a.y; r[2] = (__bf16)a.z; r[3] = (__bf16)a.w;
  r[4] = (__bf16)b.x; r[5] = (__bf16)b.y; r[6] = (__bf16)b.z; r[7] = (__bf16)b.w;
  return r;
}

__device__ __forceinline__ void gl_lds16(const bf16* g, bf16* l) {
  __builtin_amdgcn_global_load_lds((const __attribute__((address_space(1))) void*)g,
                                   (__attribute__((address_space(3))) void*)l, 16, 0, 0);
}

// fp32 -> bf16 converts: blocks [0,4096) convert x (8.39M elts), [4096,4608) convert w (1M).
__global__ __launch_bounds__(256) void cvt_pair(const float* __restrict__ x, bf16* __restrict__ xd,
                                                const float* __restrict__ ws, bf16* __restrict__ wd) {
  const int bid = blockIdx.x;
  const float* s; bf16* d; size_t idx;
  if (bid < 4096) { s = x; d = xd; idx = (size_t)bid * 256 + threadIdx.x; }
  else { s = ws; d = wd; idx = (size_t)(bid - 4096) * 256 + threadIdx.x; }
  idx *= 8;
  float4 f0 = *(const float4*)(s + idx), f1 = *(const float4*)(s + idx + 4);
  *(bf16x8*)(d + idx) = pack8(f0, f1);
}

__global__ __launch_bounds__(256) void cvt_w(const float* __restrict__ ws, bf16* __restrict__ wd) {
  size_t idx = ((size_t)blockIdx.x * 256 + threadIdx.x) * 8;
  float4 f0 = *(const float4*)(ws + idx), f1 = *(const float4*)(ws + idx + 4);
  *(bf16x8*)(wd + idx) = pack8(f0, f1);
}

// C = A(8192x1024) * W(1024x1024)^T, bf16 in, 128x128 tile, BK=64, 4 waves (2x2 of 64x64).
// Double-buffered global_load_lds prefetch; 16 K-iterations; XOR-swizzled LDS
// (chunk ^= row&7) to kill the 128B-row-stride bank conflict on ds_read_b128.
template <int MODE>
__global__ __launch_bounds__(256, 2) void mha_gemm(const bf16* __restrict__ A,
                                                   const bf16* __restrict__ W,
                                                   void* __restrict__ dstv) {
  __shared__ __align__(16) bf16 As[2][128][64];
  __shared__ __align__(16) bf16 Bs[2][128][64];
  const int tid = threadIdx.x;
  const int bm0 = blockIdx.x * 128, bn0 = blockIdx.y * 128;
  const int w = tid >> 6, lane = tid & 63, l16 = lane & 15, quad = lane >> 4;
  const int wm = (w >> 1) * 64, wn = (w & 1) * 64;
  const int swz = l16 & 7;

  // staging lane geometry: 8 rows x 8 chunks per issue; pre-swizzle the
  // global chunk so LDS[row][c] holds global chunk c^(row&7) (linear dest).
  const int srow = lane >> 3, schunk = (lane & 7) ^ (srow & 7);
  const bf16* Ag = A + (size_t)(bm0 + w * 32 + srow) * Dd + schunk * 8;
  const bf16* Wg = W + (size_t)(bn0 + w * 32 + srow) * Dd + schunk * 8;

  f32x4 acc[4][4] = {};

  // prologue: stage k-tile 0 into buf 0 (4 issues of 8 rows per matrix per wave)
#pragma unroll
  for (int i = 0; i < 4; ++i) {
    gl_lds16(Ag + (size_t)i * 8 * Dd, &As[0][w * 32 + i * 8][0]);
    gl_lds16(Wg + (size_t)i * 8 * Dd, &Bs[0][w * 32 + i * 8][0]);
  }
  __syncthreads();

  for (int kt = 0; kt < 16; ++kt) {
    const int cur = kt & 1, nxt = cur ^ 1;
    if (kt < 15) {
      const int ko = (kt + 1) * 64;
#pragma unroll
      for (int i = 0; i < 4; ++i) {
        gl_lds16(Ag + ko + (size_t)i * 8 * Dd, &As[nxt][w * 32 + i * 8][0]);
        gl_lds16(Wg + ko + (size_t)i * 8 * Dd, &Bs[nxt][w * 32 + i * 8][0]);
      }
    }
#pragma unroll
    for (int kk = 0; kk < 2; ++kk) {
      bf16x8 af[4], bw[4];
#pragma unroll
      for (int i = 0; i < 4; ++i)
        af[i] = *(bf16x8*)&As[cur][wm + i * 16 + l16][((kk * 4 + quad) ^ swz) * 8];
#pragma unroll
      for (int i = 0; i < 4; ++i)
        bw[i] = *(bf16x8*)&Bs[cur][wn + i * 16 + l16][((kk * 4 + quad) ^ swz) * 8];
#pragma unroll
      for (int mt = 0; mt < 4; ++mt)
#pragma unroll
        for (int nt = 0; nt < 4; ++nt)
          acc[mt][nt] =
              __builtin_amdgcn_mfma_f32_16x16x32_bf16(af[mt], bw[nt], acc[mt][nt], 0, 0, 0);
    }
    __syncthreads();  // drains nxt DMA (issued before compute) + orders LDS reuse
  }

  // C/D layout: col = lane&15, row = quad*4 + r
  if constexpr (MODE == 2) {
    float* out = (float*)dstv;
#pragma unroll
    for (int mt = 0; mt < 4; ++mt)
#pragma unroll
      for (int nt = 0; nt < 4; ++nt) {
        const int gcol = bn0 + wn + nt * 16 + l16;
        const int grow0 = bm0 + wm + mt * 16 + quad * 4;
#pragma unroll
        for (int r = 0; r < 4; ++r) out[(size_t)(grow0 + r) * Dd + gcol] = acc[mt][nt][r];
      }
  } else if constexpr (MODE == 1) {
    bf16* vt = (bf16*)dstv;
#pragma unroll
    for (int mt = 0; mt < 4; ++mt)
#pragma unroll
      for (int nt = 0; nt < 4; ++nt) {
        const int gcol = bn0 + wn + nt * 16 + l16;
        const int h = gcol >> 6, dk = gcol & 63;
#pragma unroll
        for (int r = 0; r < 4; ++r) {
          const int grow = bm0 + wm + mt * 16 + quad * 4 + r;
          const int b = grow >> 11, s = grow & (Ss - 1);
          vt[((size_t)(b * Hh + h) * DKk + dk) * Ss + s] = (bf16)acc[mt][nt][r];
        }
      }
  } else {
    bf16* qp = (bf16*)dstv;
#pragma unroll
    for (int mt = 0; mt < 4; ++mt)
#pragma unroll
      for (int nt = 0; nt < 4; ++nt) {
        const int gcol = bn0 + wn + nt * 16 + l16;
        const int h = gcol >> 6, dk = gcol & 63;
        const float invf = exp2f((float)(dk >> 1) * -0.4152410118609203f);
        const float sgn = (dk & 1) ? 1.0f : -1.0f;
#pragma unroll
        for (int r = 0; r < 4; ++r) {
          const int grow = bm0 + wm + mt * 16 + quad * 4 + r;
          const int b = grow >> 11, s = grow & (Ss - 1);
          const float v = acc[mt][nt][r];
          const float ov = __shfl_xor(v, 1);
          float sn, cs;
          __sincosf((float)s * invf, &sn, &cs);
          const float rot = v * cs + sgn * ov * sn;
          qp[((size_t)(b * Hh + h) * Ss + s) * DKk + dk] = (bf16)rot;
        }
      }
  }
}

// Flash attention R6 (unchanged): 128 q-rows x one (b,h) per block; 4 waves x 32 rows;
// 64-key tiles, double-buffered gl_lds; mask folded into MFMA acc init; l via ones-MFMA.
// Per-kt phase split: QK for BOTH mt with single-pass kf reads, P staged through
// per-wave Pb slice (serial write/read), single PV pass feeding both mt.
// LDS: Ks 16K dbuf + Vs 16K dbuf + P 8K = 40960 B -> 4 blocks/CU.
__global__ __launch_bounds__(256, 4) void mha_attn(const bf16* __restrict__ Qp,
                                                   const bf16* __restrict__ Kp,
                                                   const bf16* __restrict__ Vt,
                                                   const int* __restrict__ maskG,
                                                   bf16* __restrict__ Xo) {
  __shared__ __align__(16) bf16 Ks[2][64][64];  // [buf][key][dk], XOR-swizzled 16B chunks
  __shared__ __align__(16) bf16 Vs[2][64][64];  // [buf][dk][key], XOR-swizzled 16B chunks
  __shared__ __align__(16) bf16 Pbuf[4][1024];  // per-wave P slice (16 rows x 64 keys)

  constexpr float c1 = 0.18033688011112042f;   // 0.125 * log2(e)
  constexpr float c2 = -17.312340490667562f;   // -12 * log2(e)

  const int tid = threadIdx.x;
  const int bh = blockIdx.y, b = bh >> 4, h = bh & 15;
  const int q0 = blockIdx.x * 128;
  const int w = tid >> 6, lane = tid & 63, l16 = lane & 15, quad = lane >> 4;
  const int swz = l16 & 7;
  const size_t hbase = (size_t)bh * Ss * DKk;

  {  // stage Q tile [128 x 64] through the Ks dbuf area (8192 elts, exactly fits)
    bf16* Qst = &Ks[0][0][0];
    const int row = tid >> 1, hf = tid & 1;
    const bf16* src = Qp + hbase + (size_t)(q0 + row) * DKk + hf * 32;
#pragma unroll
    for (int cc = 0; cc < 4; ++cc)
      *(int4*)&Qst[(((hf * 4 + cc) * 128) + row) * 8] = *(const int4*)(src + cc * 8);
  }
  __syncthreads();
  // hoist Q fragments (A-layout: m -> q-row w*32+mt*16+l16, k=kk*32+quad*8+j)
  bf16x8 qf[2][2];
  {
    const bf16* Qst = &Ks[0][0][0];
#pragma unroll
    for (int mt = 0; mt < 2; ++mt)
#pragma unroll
      for (int kk = 0; kk < 2; ++kk)
        qf[mt][kk] = *(bf16x8*)&Qst[(((kk * 4 + quad) * 128) + w * 32 + mt * 16 + l16) * 8];
  }
  __syncthreads();  // all hoists done before K DMA overwrites Ks

  // staging lane geometry: 8 rows x 8 chunks per issue; swizzle chunk ^= row&7
  const int srow = lane >> 3, schunk = (lane & 7) ^ (srow & 7);
  const bf16* Kg = Kp + hbase + (size_t)(w * 16 + srow) * DKk + schunk * 8;
  const bf16* Vg = Vt + ((size_t)bh * DKk + w * 16 + srow) * Ss + schunk * 8;
  const int* Mg = maskG + b * Ss + l16;

  int mcur[4], mnext[4];
  // prologue: stage tile 0
#pragma unroll
  for (int i = 0; i < 2; ++i) {
    gl_lds16(Kg + (size_t)i * 8 * DKk, &Ks[0][w * 16 + i * 8][0]);
    gl_lds16(Vg + i * 8 * Ss, &Vs[0][w * 16 + i * 8][0]);
  }
#pragma unroll
  for (int nt = 0; nt < 4; ++nt) mcur[nt] = Mg[nt * 16];
  __syncthreads();  // drains tile-0 DMA

  f32x4 o[2][4] = {};
  f32x4 lo[2] = {};
  bf16* Pb = &Pbuf[w][0];

  // ones B-operand for the l-accumulating MFMA (registers only, no LDS)
  bf16x8 vones;
#pragma unroll
  for (int i = 0; i < 8; ++i) vones[i] = (__bf16)1.0f;

  for (int kt = 0; kt < 32; ++kt) {
    const int cur = kt & 1, nxt = cur ^ 1;
    if (kt < 31) {  // prefetch tile kt+1 (drained at this iteration's end barrier)
      const size_t k0n = (size_t)(kt + 1) * 64;
#pragma unroll
      for (int i = 0; i < 2; ++i) {
        gl_lds16(Kg + k0n * DKk + (size_t)i * 8 * DKk, &Ks[nxt][w * 16 + i * 8][0]);
        gl_lds16(Vg + k0n + i * 8 * Ss, &Vs[nxt][w * 16 + i * 8][0]);
      }
#pragma unroll
      for (int nt = 0; nt < 4; ++nt) mnext[nt] = Mg[k0n + nt * 16];
    }

    // ---- QK phase: S = Q K^T for BOTH mt, each kf read ONCE ----
    // mask bias folded into accumulator init: masked cols start at -1e9 ->
    // exp2 underflows to exact 0 (matches ref select)
    f32x4 sc[2][4];
#pragma unroll
    for (int nt = 0; nt < 4; ++nt) {
      const float bv = (mcur[nt] != 0) ? 0.0f : -1e9f;
#pragma unroll
      for (int r = 0; r < 4; ++r) { sc[0][nt][r] = bv; sc[1][nt][r] = bv; }
    }
#pragma unroll
    for (int kk = 0; kk < 2; ++kk)
#pragma unroll
      for (int nt = 0; nt < 4; ++nt) {
        bf16x8 kf = *(bf16x8*)&Ks[cur][nt * 16 + l16][((kk * 4 + quad) ^ swz) * 8];
        sc[0][nt] = __builtin_amdgcn_mfma_f32_16x16x32_bf16(qf[0][kk], kf, sc[0][nt], 0, 0, 0);
        sc[1][nt] = __builtin_amdgcn_mfma_f32_16x16x32_bf16(qf[1][kk], kf, sc[1][nt], 0, 0, 0);
      }

    // ---- softmax + P staging, mt0 then mt1 through the SAME Pb slice ----
    // (same-wave DS ops execute in order: write mt0 -> read pf0 -> write mt1
    //  -> read pf1 is safe)
    bf16x8 pf0[2], pf1[2];
#pragma unroll
    for (int nt = 0; nt < 4; ++nt) {
      const int c = nt * 2 + (l16 >> 3);
      const int jj = l16 & 7;
#pragma unroll
      for (int r = 0; r < 4; ++r)
        Pb[(c * 16 + quad * 4 + r) * 8 + jj] = (bf16)exp2f(fmaf(sc[0][nt][r], c1, c2));
    }
#pragma unroll
    for (int kk = 0; kk < 2; ++kk)
      pf0[kk] = *(bf16x8*)(Pb + ((kk * 4 + quad) * 16 + l16) * 8);
#pragma unroll
    for (int nt = 0; nt < 4; ++nt) {
      const int c = nt * 2 + (l16 >> 3);
      const int jj = l16 & 7;
#pragma unroll
      for (int r = 0; r < 4; ++r)
        Pb[(c * 16 + quad * 4 + r) * 8 + jj] = (bf16)exp2f(fmaf(sc[1][nt][r], c1, c2));
    }
#pragma unroll
    for (int kk = 0; kk < 2; ++kk)
      pf1[kk] = *(bf16x8*)(Pb + ((kk * 4 + quad) * 16 + l16) * 8);

    // ---- PV phase: each vf read ONCE, feeds both mt; l via ones-MFMA ----
#pragma unroll
    for (int kk = 0; kk < 2; ++kk) {
      lo[0] = __builtin_amdgcn_mfma_f32_16x16x32_bf16(pf0[kk], vones, lo[0], 0, 0, 0);
      lo[1] = __builtin_amdgcn_mfma_f32_16x16x32_bf16(pf1[kk], vones, lo[1], 0, 0, 0);
#pragma unroll
      for (int nt = 0; nt < 4; ++nt) {
        bf16x8 vf = *(bf16x8*)&Vs[cur][nt * 16 + l16][((kk * 4 + quad) ^ swz) * 8];
        o[0][nt] = __builtin_amdgcn_mfma_f32_16x16x32_bf16(pf0[kk], vf, o[0][nt], 0, 0, 0);
        o[1][nt] = __builtin_amdgcn_mfma_f32_16x16x32_bf16(pf1[kk], vf, o[1][nt], 0, 0, 0);
      }
    }
    __syncthreads();  // all waves done with buf cur; prefetch of nxt drained here
#pragma unroll
    for (int nt = 0; nt < 4; ++nt) mcur[nt] = mnext[nt];
  }

  // epilogue: O / l -> Xo [B*S, H*DK] bf16  (lo identical across the 16 cols of a row)
#pragma unroll
  for (int mt = 0; mt < 2; ++mt)
#pragma unroll
    for (int nt = 0; nt < 4; ++nt)
#pragma unroll
      for (int r = 0; r < 4; ++r) {
        const int srw = q0 + w * 32 + mt * 16 + quad * 4 + r;
        const int dk = nt * 16 + l16;
        Xo[(size_t)(b * Ss + srw) * Dd + h * DKk + dk] = (bf16)(o[mt][nt][r] / lo[mt][r]);
      }
}

}  // namespace

extern "C" void kernel_launch(void* const* d_in, const int* in_sizes, int n_in,
                              void* d_out, int out_size, void* d_ws, size_t ws_size,
                              hipStream_t stream) {
  (void)in_sizes; (void)n_in; (void)out_size; (void)ws_size;
  const float* q = (const float*)d_in[0];
  const float* k = (const float*)d_in[1];
  const float* v = (const float*)d_in[2];
  const int* mask = (const int*)d_in[3];
  const float* w_q = (const float*)d_in[4];
  const float* w_k = (const float*)d_in[5];
  const float* w_v = (const float*)d_in[6];
  const float* w_o = (const float*)d_in[7];
  float* out = (float*)d_out;

  const size_t n_elem = (size_t)Bb * Hh * Ss * DKk;  // 8.39M
  bf16* buf0 = (bf16*)d_ws;         // 16.78 MB: bf16 A staging, later Xo
  bf16* wbuf = buf0 + n_elem;       // 2 MB: bf16 weight staging (reused per GEMM)
  bf16* Qp = wbuf + (1 << 20);      // [B,H,S,DK] rope'd
  bf16* Kp = Qp + n_elem;           // [B,H,S,DK] rope'd
  bf16* Vt = Kp + n_elem;           // [B,H,DK,S]
  // total ws use: 69.2 MB

  dim3 g(64, 8), blk(256);
  cvt_pair<<<4608, blk, 0, stream>>>(q, buf0, w_q, wbuf);
  mha_gemm<0><<<g, blk, 0, stream>>>(buf0, wbuf, (void*)Qp);
  cvt_pair<<<4608, blk, 0, stream>>>(k, buf0, w_k, wbuf);
  mha_gemm<0><<<g, blk, 0, stream>>>(buf0, wbuf, (void*)Kp);
  cvt_pair<<<4608, blk, 0, stream>>>(v, buf0, w_v, wbuf);
  mha_gemm<1><<<g, blk, 0, stream>>>(buf0, wbuf, (void*)Vt);
  mha_attn<<<dim3(16, 64), blk, 0, stream>>>(Qp, Kp, Vt, mask, buf0);
  cvt_w<<<512, blk, 0, stream>>>(w_o, wbuf);
  mha_gemm<2><<<g, blk, 0, stream>>>(buf0, wbuf, (void*)out);
}

// Round 3
// 376.619 us; speedup vs baseline: 1.0822x; 1.0376x over previous
//
#include <hip/hip_runtime.h>
#include <hip/hip_bf16.h>
#include <math.h>

// MHA block: B=4, S=2048, D=1024, H=16, DK=64.
// R8: QKV GEMMs fused into ONE launch (blockIdx.z selects q/k/v), BK back to 32
// (32KB LDS) + __launch_bounds__(256,4) => 4 resident blocks/CU. Theory: R7
// showed per-iteration tweaks (BK=64+swizzle) are neutral; the GEMM cost is
// exposed staging latency with only 2 lock-step blocks/CU. 1536-block fused
// launch gives independent blocks whose stalls interleave (m114 mechanism).
// cvt launches also fused (one cvt6). Runtime ws_size check with sequential
// fallback (R7 layout) if workspace < 107MB. Attn unchanged from R6.

namespace {

constexpr int Bb = 4, Ss = 2048, Dd = 1024, Hh = 16, DKk = 64;
constexpr size_t NElem = (size_t)Bb * Hh * Ss * DKk;  // 8388608
constexpr size_t WElem = (size_t)Dd * Dd;             // 1048576

typedef __bf16 bf16;
typedef __attribute__((ext_vector_type(8))) __bf16 bf16x8;
typedef __attribute__((ext_vector_type(4))) float f32x4;

__device__ __forceinline__ bf16x8 pack8(float4 a, float4 b) {
  bf16x8 r;
  r[0] = (__bf16)a.x; r[1] = (__bf16)a.y; r[2] = (__bf16)a.z; r[3] = (__bf16)a.w;
  r[4] = (__bf16)b.x; r[5] = (__bf16)b.y; r[6] = (__bf16)b.z; r[7] = (__bf16)b.w;
  return r;
}

__device__ __forceinline__ void gl_lds16(const bf16* g, bf16* l) {
  __builtin_amdgcn_global_load_lds((const __attribute__((address_space(1))) void*)g,
                                   (__attribute__((address_space(3))) void*)l, 16, 0, 0);
}

// fused fp32->bf16: blocks [0,12288) convert q,k,v (4096 blocks each);
// [12288,13824) convert wq,wk,wv (512 blocks each).
__global__ __launch_bounds__(256) void cvt6(const float* __restrict__ q,
                                            const float* __restrict__ k,
                                            const float* __restrict__ v,
                                            const float* __restrict__ wq,
                                            const float* __restrict__ wk,
                                            const float* __restrict__ wv,
                                            bf16* __restrict__ xd, bf16* __restrict__ wd) {
  const int bid = blockIdx.x;
  const float* s; bf16* d; size_t idx;
  if (bid < 12288) {
    const int t = bid >> 12;
    s = (t == 0) ? q : (t == 1) ? k : v;
    d = xd + (size_t)t * NElem;
    idx = ((size_t)(bid & 4095) * 256 + threadIdx.x) * 8;
  } else {
    const int t = (bid - 12288) >> 9;
    s = (t == 0) ? wq : (t == 1) ? wk : wv;
    d = wd + (size_t)t * WElem;
    idx = ((size_t)((bid - 12288) & 511) * 256 + threadIdx.x) * 8;
  }
  float4 f0 = *(const float4*)(s + idx), f1 = *(const float4*)(s + idx + 4);
  *(bf16x8*)(d + idx) = pack8(f0, f1);
}

// legacy pair-convert for the fallback path
__global__ __launch_bounds__(256) void cvt_pair(const float* __restrict__ x, bf16* __restrict__ xd,
                                                const float* __restrict__ ws, bf16* __restrict__ wd) {
  const int bid = blockIdx.x;
  const float* s; bf16* d; size_t idx;
  if (bid < 4096) { s = x; d = xd; idx = (size_t)bid * 256 + threadIdx.x; }
  else { s = ws; d = wd; idx = (size_t)(bid - 4096) * 256 + threadIdx.x; }
  idx *= 8;
  float4 f0 = *(const float4*)(s + idx), f1 = *(const float4*)(s + idx + 4);
  *(bf16x8*)(d + idx) = pack8(f0, f1);
}

__global__ __launch_bounds__(256) void cvt_w(const float* __restrict__ ws, bf16* __restrict__ wd) {
  size_t idx = ((size_t)blockIdx.x * 256 + threadIdx.x) * 8;
  float4 f0 = *(const float4*)(ws + idx), f1 = *(const float4*)(ws + idx + 4);
  *(bf16x8*)(wd + idx) = pack8(f0, f1);
}

// C = A(8192x1024) * W(1024x1024)^T, bf16 in, 128x128 tile, BK=32, 4 waves (2x2 of 64x64).
// Double-buffered global_load_lds prefetch. MODE 0: rope-store; 1: V-transpose-store;
// 2: fp32 plain store (out proj); 3: fused QKV (blockIdx.z selects tensor; z<2 rope,
// z==2 transpose). launch_bounds(256,4): 32KB LDS + <=128 VGPR -> 4 blocks/CU.
template <int MODE>
__global__ __launch_bounds__(256, 4) void mha_gemm(const bf16* __restrict__ A,
                                                   const bf16* __restrict__ W,
                                                   void* __restrict__ dstv) {
  __shared__ __align__(16) bf16 As[2][128][32];
  __shared__ __align__(16) bf16 Bs[2][128][32];
  const int tid = threadIdx.x;
  const int z = (MODE == 3) ? blockIdx.z : 0;
  const int bm0 = blockIdx.x * 128, bn0 = blockIdx.y * 128;
  const int w = tid >> 6, lane = tid & 63, l16 = lane & 15, quad = lane >> 4;
  const int wm = (w >> 1) * 64, wn = (w & 1) * 64;
  const int lr = lane >> 2, lc = (lane & 3) * 8;

  const bf16* Ag = A + (size_t)z * NElem + (size_t)(bm0 + w * 32 + lr) * Dd + lc;
  const bf16* Wg = W + (size_t)z * WElem + (size_t)(bn0 + w * 32 + lr) * Dd + lc;

  f32x4 acc[4][4] = {};

  // prologue: stage k-tile 0 into buf 0
  gl_lds16(Ag, &As[0][w * 32][0]);
  gl_lds16(Ag + 16 * Dd, &As[0][w * 32 + 16][0]);
  gl_lds16(Wg, &Bs[0][w * 32][0]);
  gl_lds16(Wg + 16 * Dd, &Bs[0][w * 32 + 16][0]);
  __syncthreads();

  for (int kt = 0; kt < 32; ++kt) {
    const int cur = kt & 1, nxt = cur ^ 1;
    if (kt < 31) {
      const int ko = (kt + 1) * 32;
      gl_lds16(Ag + ko, &As[nxt][w * 32][0]);
      gl_lds16(Ag + ko + 16 * Dd, &As[nxt][w * 32 + 16][0]);
      gl_lds16(Wg + ko, &Bs[nxt][w * 32][0]);
      gl_lds16(Wg + ko + 16 * Dd, &Bs[nxt][w * 32 + 16][0]);
    }
    bf16x8 af[4], bw[4];
#pragma unroll
    for (int i = 0; i < 4; ++i) af[i] = *(bf16x8*)&As[cur][wm + i * 16 + l16][quad * 8];
#pragma unroll
    for (int i = 0; i < 4; ++i) bw[i] = *(bf16x8*)&Bs[cur][wn + i * 16 + l16][quad * 8];
#pragma unroll
    for (int mt = 0; mt < 4; ++mt)
#pragma unroll
      for (int nt = 0; nt < 4; ++nt)
        acc[mt][nt] =
            __builtin_amdgcn_mfma_f32_16x16x32_bf16(af[mt], bw[nt], acc[mt][nt], 0, 0, 0);
    __syncthreads();  // drains nxt DMA (issued before compute) + orders LDS reuse
  }

  // C/D layout: col = lane&15, row = quad*4 + r
  const bool do_rope = (MODE == 0) || (MODE == 3 && z < 2);
  const bool do_vt = (MODE == 1) || (MODE == 3 && z == 2);

  if constexpr (MODE == 2) {
    float* out = (float*)dstv;
#pragma unroll
    for (int mt = 0; mt < 4; ++mt)
#pragma unroll
      for (int nt = 0; nt < 4; ++nt) {
        const int gcol = bn0 + wn + nt * 16 + l16;
        const int grow0 = bm0 + wm + mt * 16 + quad * 4;
#pragma unroll
        for (int r = 0; r < 4; ++r) out[(size_t)(grow0 + r) * Dd + gcol] = acc[mt][nt][r];
      }
  } else {
    if (do_vt) {
      bf16* vt = (bf16*)dstv + (MODE == 3 ? 2 * NElem : 0);
#pragma unroll
      for (int mt = 0; mt < 4; ++mt)
#pragma unroll
        for (int nt = 0; nt < 4; ++nt) {
          const int gcol = bn0 + wn + nt * 16 + l16;
          const int h = gcol >> 6, dk = gcol & 63;
#pragma unroll
          for (int r = 0; r < 4; ++r) {
            const int grow = bm0 + wm + mt * 16 + quad * 4 + r;
            const int b = grow >> 11, s = grow & (Ss - 1);
            vt[((size_t)(b * Hh + h) * DKk + dk) * Ss + s] = (bf16)acc[mt][nt][r];
          }
        }
    } else if (do_rope) {
      bf16* qp = (bf16*)dstv + (MODE == 3 ? (size_t)z * NElem : 0);
#pragma unroll
      for (int mt = 0; mt < 4; ++mt)
#pragma unroll
        for (int nt = 0; nt < 4; ++nt) {
          const int gcol = bn0 + wn + nt * 16 + l16;
          const int h = gcol >> 6, dk = gcol & 63;
          const float invf = exp2f((float)(dk >> 1) * -0.4152410118609203f);
          const float sgn = (dk & 1) ? 1.0f : -1.0f;
#pragma unroll
          for (int r = 0; r < 4; ++r) {
            const int grow = bm0 + wm + mt * 16 + quad * 4 + r;
            const int b = grow >> 11, s = grow & (Ss - 1);
            const float v = acc[mt][nt][r];
            const float ov = __shfl_xor(v, 1);
            float sn, cs;
            __sincosf((float)s * invf, &sn, &cs);
            const float rot = v * cs + sgn * ov * sn;
            qp[((size_t)(b * Hh + h) * Ss + s) * DKk + dk] = (bf16)rot;
          }
        }
    }
  }
}

// Flash attention (unchanged from R6): 128 q-rows x one (b,h) per block; 4 waves x
// 32 rows; 64-key tiles, double-buffered gl_lds; mask folded into MFMA acc init;
// l via ones-MFMA; per-kt phase split with single-pass kf/vf reads.
// LDS: Ks 16K dbuf + Vs 16K dbuf + P 8K = 40960 B -> 4 blocks/CU.
__global__ __launch_bounds__(256, 4) void mha_attn(const bf16* __restrict__ Qp,
                                                   const bf16* __restrict__ Kp,
                                                   const bf16* __restrict__ Vt,
                                                   const int* __restrict__ maskG,
                                                   bf16* __restrict__ Xo) {
  __shared__ __align__(16) bf16 Ks[2][64][64];  // [buf][key][dk], XOR-swizzled 16B chunks
  __shared__ __align__(16) bf16 Vs[2][64][64];  // [buf][dk][key], XOR-swizzled 16B chunks
  __shared__ __align__(16) bf16 Pbuf[4][1024];  // per-wave P slice (16 rows x 64 keys)

  constexpr float c1 = 0.18033688011112042f;   // 0.125 * log2(e)
  constexpr float c2 = -17.312340490667562f;   // -12 * log2(e)

  const int tid = threadIdx.x;
  const int bh = blockIdx.y, b = bh >> 4, h = bh & 15;
  const int q0 = blockIdx.x * 128;
  const int w = tid >> 6, lane = tid & 63, l16 = lane & 15, quad = lane >> 4;
  const int swz = l16 & 7;
  const size_t hbase = (size_t)bh * Ss * DKk;

  {  // stage Q tile [128 x 64] through the Ks dbuf area (8192 elts, exactly fits)
    bf16* Qst = &Ks[0][0][0];
    const int row = tid >> 1, hf = tid & 1;
    const bf16* src = Qp + hbase + (size_t)(q0 + row) * DKk + hf * 32;
#pragma unroll
    for (int cc = 0; cc < 4; ++cc)
      *(int4*)&Qst[(((hf * 4 + cc) * 128) + row) * 8] = *(const int4*)(src + cc * 8);
  }
  __syncthreads();
  // hoist Q fragments (A-layout: m -> q-row w*32+mt*16+l16, k=kk*32+quad*8+j)
  bf16x8 qf[2][2];
  {
    const bf16* Qst = &Ks[0][0][0];
#pragma unroll
    for (int mt = 0; mt < 2; ++mt)
#pragma unroll
      for (int kk = 0; kk < 2; ++kk)
        qf[mt][kk] = *(bf16x8*)&Qst[(((kk * 4 + quad) * 128) + w * 32 + mt * 16 + l16) * 8];
  }
  __syncthreads();  // all hoists done before K DMA overwrites Ks

  // staging lane geometry: 8 rows x 8 chunks per issue; swizzle chunk ^= row&7
  const int srow = lane >> 3, schunk = (lane & 7) ^ (srow & 7);
  const bf16* Kg = Kp + hbase + (size_t)(w * 16 + srow) * DKk + schunk * 8;
  const bf16* Vg = Vt + ((size_t)bh * DKk + w * 16 + srow) * Ss + schunk * 8;
  const int* Mg = maskG + b * Ss + l16;

  int mcur[4], mnext[4];
  // prologue: stage tile 0
#pragma unroll
  for (int i = 0; i < 2; ++i) {
    gl_lds16(Kg + (size_t)i * 8 * DKk, &Ks[0][w * 16 + i * 8][0]);
    gl_lds16(Vg + i * 8 * Ss, &Vs[0][w * 16 + i * 8][0]);
  }
#pragma unroll
  for (int nt = 0; nt < 4; ++nt) mcur[nt] = Mg[nt * 16];
  __syncthreads();  // drains tile-0 DMA

  f32x4 o[2][4] = {};
  f32x4 lo[2] = {};
  bf16* Pb = &Pbuf[w][0];

  // ones B-operand for the l-accumulating MFMA (registers only, no LDS)
  bf16x8 vones;
#pragma unroll
  for (int i = 0; i < 8; ++i) vones[i] = (__bf16)1.0f;

  for (int kt = 0; kt < 32; ++kt) {
    const int cur = kt & 1, nxt = cur ^ 1;
    if (kt < 31) {  // prefetch tile kt+1 (drained at this iteration's end barrier)
      const size_t k0n = (size_t)(kt + 1) * 64;
#pragma unroll
      for (int i = 0; i < 2; ++i) {
        gl_lds16(Kg + k0n * DKk + (size_t)i * 8 * DKk, &Ks[nxt][w * 16 + i * 8][0]);
        gl_lds16(Vg + k0n + i * 8 * Ss, &Vs[nxt][w * 16 + i * 8][0]);
      }
#pragma unroll
      for (int nt = 0; nt < 4; ++nt) mnext[nt] = Mg[k0n + nt * 16];
    }

    // ---- QK phase: S = Q K^T for BOTH mt, each kf read ONCE ----
    f32x4 sc[2][4];
#pragma unroll
    for (int nt = 0; nt < 4; ++nt) {
      const float bv = (mcur[nt] != 0) ? 0.0f : -1e9f;
#pragma unroll
      for (int r = 0; r < 4; ++r) { sc[0][nt][r] = bv; sc[1][nt][r] = bv; }
    }
#pragma unroll
    for (int kk = 0; kk < 2; ++kk)
#pragma unroll
      for (int nt = 0; nt < 4; ++nt) {
        bf16x8 kf = *(bf16x8*)&Ks[cur][nt * 16 + l16][((kk * 4 + quad) ^ swz) * 8];
        sc[0][nt] = __builtin_amdgcn_mfma_f32_16x16x32_bf16(qf[0][kk], kf, sc[0][nt], 0, 0, 0);
        sc[1][nt] = __builtin_amdgcn_mfma_f32_16x16x32_bf16(qf[1][kk], kf, sc[1][nt], 0, 0, 0);
      }

    // ---- softmax + P staging, mt0 then mt1 through the SAME Pb slice ----
    bf16x8 pf0[2], pf1[2];
#pragma unroll
    for (int nt = 0; nt < 4; ++nt) {
      const int c = nt * 2 + (l16 >> 3);
      const int jj = l16 & 7;
#pragma unroll
      for (int r = 0; r < 4; ++r)
        Pb[(c * 16 + quad * 4 + r) * 8 + jj] = (bf16)exp2f(fmaf(sc[0][nt][r], c1, c2));
    }
#pragma unroll
    for (int kk = 0; kk < 2; ++kk)
      pf0[kk] = *(bf16x8*)(Pb + ((kk * 4 + quad) * 16 + l16) * 8);
#pragma unroll
    for (int nt = 0; nt < 4; ++nt) {
      const int c = nt * 2 + (l16 >> 3);
      const int jj = l16 & 7;
#pragma unroll
      for (int r = 0; r < 4; ++r)
        Pb[(c * 16 + quad * 4 + r) * 8 + jj] = (bf16)exp2f(fmaf(sc[1][nt][r], c1, c2));
    }
#pragma unroll
    for (int kk = 0; kk < 2; ++kk)
      pf1[kk] = *(bf16x8*)(Pb + ((kk * 4 + quad) * 16 + l16) * 8);

    // ---- PV phase: each vf read ONCE, feeds both mt; l via ones-MFMA ----
#pragma unroll
    for (int kk = 0; kk < 2; ++kk) {
      lo[0] = __builtin_amdgcn_mfma_f32_16x16x32_bf16(pf0[kk], vones, lo[0], 0, 0, 0);
      lo[1] = __builtin_amdgcn_mfma_f32_16x16x32_bf16(pf1[kk], vones, lo[1], 0, 0, 0);
#pragma unroll
      for (int nt = 0; nt < 4; ++nt) {
        bf16x8 vf = *(bf16x8*)&Vs[cur][nt * 16 + l16][((kk * 4 + quad) ^ swz) * 8];
        o[0][nt] = __builtin_amdgcn_mfma_f32_16x16x32_bf16(pf0[kk], vf, o[0][nt], 0, 0, 0);
        o[1][nt] = __builtin_amdgcn_mfma_f32_16x16x32_bf16(pf1[kk], vf, o[1][nt], 0, 0, 0);
      }
    }
    __syncthreads();  // all waves done with buf cur; prefetch of nxt drained here
#pragma unroll
    for (int nt = 0; nt < 4; ++nt) mcur[nt] = mnext[nt];
  }

  // epilogue: O / l -> Xo [B*S, H*DK] bf16  (lo identical across the 16 cols of a row)
#pragma unroll
  for (int mt = 0; mt < 2; ++mt)
#pragma unroll
    for (int nt = 0; nt < 4; ++nt)
#pragma unroll
      for (int r = 0; r < 4; ++r) {
        const int srw = q0 + w * 32 + mt * 16 + quad * 4 + r;
        const int dk = nt * 16 + l16;
        Xo[(size_t)(b * Ss + srw) * Dd + h * DKk + dk] = (bf16)(o[mt][nt][r] / lo[mt][r]);
      }
}

}  // namespace

extern "C" void kernel_launch(void* const* d_in, const int* in_sizes, int n_in,
                              void* d_out, int out_size, void* d_ws, size_t ws_size,
                              hipStream_t stream) {
  (void)in_sizes; (void)n_in; (void)out_size;
  const float* q = (const float*)d_in[0];
  const float* k = (const float*)d_in[1];
  const float* v = (const float*)d_in[2];
  const int* mask = (const int*)d_in[3];
  const float* w_q = (const float*)d_in[4];
  const float* w_k = (const float*)d_in[5];
  const float* w_v = (const float*)d_in[6];
  const float* w_o = (const float*)d_in[7];
  float* out = (float*)d_out;

  dim3 blk(256);
  const size_t fused_bytes = (6 * NElem + 3 * WElem) * sizeof(bf16);  // ~107 MB

  if (ws_size >= fused_bytes) {
    // fused path: Ab = xq,xk,xv bf16 | Wb = wq,wk,wv bf16 | Db = Qp,Kp,Vt
    bf16* Ab = (bf16*)d_ws;
    bf16* Wb = Ab + 3 * NElem;
    bf16* Db = Wb + 3 * WElem;
    bf16* Qp = Db;
    bf16* Kp = Db + NElem;
    bf16* Vt = Db + 2 * NElem;
    bf16* Xo = Ab;  // xq dead after QKV GEMMs

    cvt6<<<13824, blk, 0, stream>>>(q, k, v, w_q, w_k, w_v, Ab, Wb);
    mha_gemm<3><<<dim3(64, 8, 3), blk, 0, stream>>>(Ab, Wb, (void*)Db);
    mha_attn<<<dim3(16, 64), blk, 0, stream>>>(Qp, Kp, Vt, mask, Xo);
    cvt_w<<<512, blk, 0, stream>>>(w_o, Wb);
    mha_gemm<2><<<dim3(64, 8), blk, 0, stream>>>(Xo, Wb, (void*)out);
  } else {
    // fallback: sequential (R7 layout, 69.2 MB)
    bf16* buf0 = (bf16*)d_ws;
    bf16* wbuf = buf0 + NElem;
    bf16* Qp = wbuf + WElem;
    bf16* Kp = Qp + NElem;
    bf16* Vt = Kp + NElem;

    dim3 g(64, 8);
    cvt_pair<<<4608, blk, 0, stream>>>(q, buf0, w_q, wbuf);
    mha_gemm<0><<<g, blk, 0, stream>>>(buf0, wbuf, (void*)Qp);
    cvt_pair<<<4608, blk, 0, stream>>>(k, buf0, w_k, wbuf);
    mha_gemm<0><<<g, blk, 0, stream>>>(buf0, wbuf, (void*)Kp);
    cvt_pair<<<4608, blk, 0, stream>>>(v, buf0, w_v, wbuf);
    mha_gemm<1><<<g, blk, 0, stream>>>(buf0, wbuf, (void*)Vt);
    mha_attn<<<dim3(16, 64), blk, 0, stream>>>(Qp, Kp, Vt, mask, buf0);
    cvt_w<<<512, blk, 0, stream>>>(w_o, wbuf);
    mha_gemm<2><<<g, blk, 0, stream>>>(buf0, wbuf, (void*)out);
  }
}